// Round 1
// baseline (163.754 us; speedup 1.0000x reference)
//
#include <hip/hip_runtime.h>
#include <math.h>

#define NB 8
#define NC 3
#define HH 144
#define WW 144
#define NPAT 2304          // 48*48 patches of the 144x144 images
#define MCAT 3024          // 2304 + 576 + 144
#define CHUNK 336          // 3024 = 9 * 336
#define BLOCKS_PER_B 36    // 2304 / 64
#define NBLK_SCORE (NB * BLOCKS_PER_B)   // 288

__device__ __forceinline__ int iclamp(int v, int lo, int hi) {
    return v < lo ? lo : (v > hi ? hi : v);
}

// ---- bicubic resize, H axis.  scale in {2,4}; frac is always 0.5 so the
// 4-tap weights are the constants {-0.09375, 0.59375, 0.59375, -0.09375}.
__global__ void resize_h_kernel(const float* __restrict__ src, float* __restrict__ dst,
                                int H_out, int scale) {
    int idx = blockIdx.x * blockDim.x + threadIdx.x;
    int total = NB * NC * H_out * WW;
    if (idx >= total) return;
    int w  = idx % WW;
    int h  = (idx / WW) % H_out;
    int bc = idx / (WW * H_out);
    // coords = (h+0.5)*scale - 0.5 ; base = floor = scale*h + scale/2 - 1 ; taps base-1..base+2
    int t0 = scale * h + (scale >> 1) - 2;
    const float* s = src + (size_t)bc * HH * WW + w;
    float acc = 0.0f;
    acc += -0.09375f * s[(size_t)iclamp(t0 + 0, 0, HH - 1) * WW];
    acc +=  0.59375f * s[(size_t)iclamp(t0 + 1, 0, HH - 1) * WW];
    acc +=  0.59375f * s[(size_t)iclamp(t0 + 2, 0, HH - 1) * WW];
    acc += -0.09375f * s[(size_t)iclamp(t0 + 3, 0, HH - 1) * WW];
    dst[idx] = acc;
}

// ---- bicubic resize, W axis.  src is [NB*NC, H, 144] -> dst [NB*NC, H, W_out]
__global__ void resize_w_kernel(const float* __restrict__ src, float* __restrict__ dst,
                                int H, int W_out, int scale) {
    int idx = blockIdx.x * blockDim.x + threadIdx.x;
    int total = NB * NC * H * W_out;
    if (idx >= total) return;
    int w  = idx % W_out;
    int h  = (idx / W_out) % H;
    int bc = idx / (W_out * H);
    int t0 = scale * w + (scale >> 1) - 2;
    const float* s = src + ((size_t)bc * H + h) * WW;
    float acc = 0.0f;
    acc += -0.09375f * s[iclamp(t0 + 0, 0, WW - 1)];
    acc +=  0.59375f * s[iclamp(t0 + 1, 0, WW - 1)];
    acc +=  0.59375f * s[iclamp(t0 + 2, 0, WW - 1)];
    acc += -0.09375f * s[iclamp(t0 + 3, 0, WW - 1)];
    dst[idx] = acc;
}

// ---- 3x3 gram of non-overlapping 3x3 patches, /27
__global__ void patch_kernel(const float* __restrict__ src, int H, int W,
                             float* __restrict__ dst, int bstride, int doff) {
    int np  = (H / 3) * (W / 3);
    int idx = blockIdx.x * blockDim.x + threadIdx.x;
    if (idx >= NB * np) return;
    int b  = idx / np;
    int n  = idx % np;
    int PW = W / 3;
    int ph = n / PW, pw = n % PW;
    float p[3][9];
#pragma unroll
    for (int c = 0; c < 3; c++) {
        const float* s = src + ((size_t)b * NC + c) * H * W + (size_t)(ph * 3) * W + pw * 3;
#pragma unroll
        for (int i = 0; i < 3; i++)
#pragma unroll
            for (int j = 0; j < 3; j++)
                p[c][i * 3 + j] = s[i * W + j];
    }
    float* d = dst + (size_t)b * bstride + (size_t)(doff + n) * 9;
#pragma unroll
    for (int c = 0; c < 3; c++)
#pragma unroll
        for (int e = 0; e < 3; e++) {
            float g = 0.0f;
#pragma unroll
            for (int q = 0; q < 9; q++) g += p[c][q] * p[e][q];
            d[c * 3 + e] = g / 27.0f;
        }
}

// ---- score + argmin + |p1 - sel| partial sums.
// Block = 256 threads = 64 patches x 4 candidate-slices. 288 blocks (36/batch).
__global__ __launch_bounds__(256) void score_kernel(const float* __restrict__ p1,
                                                    const float* __restrict__ p2cat,
                                                    float* __restrict__ partials) {
    __shared__ float cand[CHUNK * 12];   // rows padded to 12 floats
    __shared__ float y2s[CHUNK];
    __shared__ float wsum[4];

    int t     = threadIdx.x;
    int blk   = blockIdx.x;
    int b     = blk / BLOCKS_PER_B;
    int n     = (blk % BLOCKS_PER_B) * 64 + (t >> 2);
    int slice = t & 3;

    const float* P1 = p1    + ((size_t)b * NPAT + n) * 9;
    const float* P2 = p2cat + ((size_t)b * MCAT + n) * 9;   // first 2304 rows of p2cat == p2
    const float* CB = p2cat + (size_t)b * MCAT * 9;

    float a1[9], a2[9];
#pragma unroll
    for (int j = 0; j < 9; j++) { a1[j] = P1[j]; a2[j] = P2[j]; }
    float x21 = 0.0f, x22 = 0.0f;
#pragma unroll
    for (int j = 0; j < 9; j++) x21 += a1[j] * a1[j];
#pragma unroll
    for (int j = 0; j < 9; j++) x22 += a2[j] * a2[j];

    float best  = INFINITY;
    int   besti = 0x7fffffff;

    for (int cb = 0; cb < MCAT; cb += CHUNK) {
        // stage chunk into LDS (pad rows to 12 floats)
        for (int i = t; i < CHUNK * 9; i += 256) {
            int c = i / 9, j = i % 9;
            cand[c * 12 + j] = CB[(size_t)cb * 9 + i];
        }
        // y^2 per candidate (read from global, same 9-term order as reference)
        for (int c = t; c < CHUNK; c += 256) {
            const float* cc = CB + (size_t)(cb + c) * 9;
            float s = 0.0f;
#pragma unroll
            for (int j = 0; j < 9; j++) s += cc[j] * cc[j];
            y2s[c] = s;
        }
        __syncthreads();

        for (int i = slice; i < CHUNK; i += 4) {
            const float* cv = cand + i * 12;
            float y2 = y2s[i];
            float d1 = 0.0f, d2 = 0.0f;
#pragma unroll
            for (int j = 0; j < 9; j++) { float v = cv[j]; d1 += a1[j] * v; d2 += a2[j] * v; }
            float s1 = x21 + y2 - 2.0f * d1;
            float s2 = x22 + y2 - 2.0f * d2;
            float sc = 1.0f * s1 + 1.0f * s2;   // ALPHA = BETA = 1
            int   cg = cb + i;
            if (sc < best || (sc == best && cg < besti)) { best = sc; besti = cg; }
        }
        __syncthreads();
    }

    // lexicographic (score, idx) min across the 4 slices (lanes 4g..4g+3)
#pragma unroll
    for (int m = 1; m < 4; m <<= 1) {
        float ob = __shfl_xor(best, m);
        int   oi = __shfl_xor(besti, m);
        if (ob < best || (ob == best && oi < besti)) { best = ob; besti = oi; }
    }

    float local = 0.0f;
    if (slice == 0) {
        const float* sel = CB + (size_t)besti * 9;
#pragma unroll
        for (int j = 0; j < 9; j++) local += fabsf(a1[j] - sel[j]);
    }
    // wave sum then block sum (fixed order -> deterministic)
#pragma unroll
    for (int m = 1; m < 64; m <<= 1) local += __shfl_xor(local, m);
    if ((t & 63) == 0) wsum[t >> 6] = local;
    __syncthreads();
    if (t == 0) partials[blk] = (wsum[0] + wsum[1]) + (wsum[2] + wsum[3]);
}

__global__ void final_kernel(const float* __restrict__ partials, float* __restrict__ out) {
    int lane = threadIdx.x;
    float s = 0.0f;
    for (int i = lane; i < NBLK_SCORE; i += 64) s += partials[i];
#pragma unroll
    for (int m = 1; m < 64; m <<= 1) s += __shfl_xor(s, m);
    if (lane == 0) out[0] = s / 165888.0f;   // mean over 8*2304*9
}

extern "C" void kernel_launch(void* const* d_in, const int* in_sizes, int n_in,
                              void* d_out, int out_size, void* d_ws, size_t ws_size,
                              hipStream_t stream) {
    const float* x  = (const float*)d_in[0];
    const float* gt = (const float*)d_in[1];
    float* out = (float*)d_out;

    float* ws   = (float*)d_ws;
    float* tmp2 = ws;                         // [8,3,72,144]  = 248832
    float* tmp4 = tmp2 + NB * NC * 72 * 144;  // [8,3,36,144]  = 124416
    float* gt2  = tmp4 + NB * NC * 36 * 144;  // [8,3,72,72]   = 124416
    float* gt4  = gt2  + NB * NC * 72 * 72;   // [8,3,36,36]   =  31104
    float* p1   = gt4  + NB * NC * 36 * 36;   // [8,2304,9]    = 165888
    float* p2c  = p1   + (size_t)NB * NPAT * 9; // [8,3024,9]  = 217728
    float* parts= p2c  + (size_t)NB * MCAT * 9; // [288]

    // resizes (H pass then W pass, matching the reference axis order)
    {
        int tot = NB * NC * 72 * 144;
        resize_h_kernel<<<(tot + 255) / 256, 256, 0, stream>>>(gt, tmp2, 72, 2);
    }
    {
        int tot = NB * NC * 36 * 144;
        resize_h_kernel<<<(tot + 255) / 256, 256, 0, stream>>>(gt, tmp4, 36, 4);
    }
    {
        int tot = NB * NC * 72 * 72;
        resize_w_kernel<<<(tot + 255) / 256, 256, 0, stream>>>(tmp2, gt2, 72, 72, 2);
    }
    {
        int tot = NB * NC * 36 * 36;
        resize_w_kernel<<<(tot + 255) / 256, 256, 0, stream>>>(tmp4, gt4, 36, 36, 4);
    }

    // patches: p1 from x; p2cat rows [0,2304)=gt, [2304,2880)=gt_2, [2880,3024)=gt_4
    patch_kernel<<<(NB * NPAT + 255) / 256, 256, 0, stream>>>(x,  144, 144, p1,  NPAT * 9, 0);
    patch_kernel<<<(NB * NPAT + 255) / 256, 256, 0, stream>>>(gt, 144, 144, p2c, MCAT * 9, 0);
    patch_kernel<<<(NB * 576 + 255) / 256, 256, 0, stream>>>(gt2, 72, 72,  p2c, MCAT * 9, NPAT);
    patch_kernel<<<(NB * 144 + 255) / 256, 256, 0, stream>>>(gt4, 36, 36,  p2c, MCAT * 9, NPAT + 576);

    score_kernel<<<NBLK_SCORE, 256, 0, stream>>>(p1, p2c, parts);
    final_kernel<<<1, 64, 0, stream>>>(parts, out);
}

// Round 2
// 85.550 us; speedup vs baseline: 1.9141x; 1.9141x over previous
//
#include <hip/hip_runtime.h>
#include <math.h>

#define NB 8
#define NC 3
#define HH 144
#define WW 144
#define NPAT 2304          // 48*48 patches of the 144x144 images
#define MCAT 3024          // 2304 + 576 + 144
#define CHUNK 336          // 3024 = 9 * 336
#define PAD 13             // 13 coprime with 32 -> conflict-free strided rows
#define PPB 16             // patches per block
#define PPT 2              // patches per thread
#define BLOCKS_PER_B (NPAT / PPB)        // 144
#define NBLK_SCORE (NB * BLOCKS_PER_B)   // 1152

__device__ __forceinline__ int iclamp(int v, int lo, int hi) {
    return v < lo ? lo : (v > hi ? hi : v);
}

// ---- fused bicubic H-pass for both scales (frac always 0.5 -> constant taps)
// range [0, T2): scale 2 -> tmp2 [8,3,72,144]; range [T2, T2+T4): scale 4 -> tmp4 [8,3,36,144]
__global__ void resize_h_all(const float* __restrict__ gt,
                             float* __restrict__ tmp2, float* __restrict__ tmp4) {
    const int T2 = NB * NC * 72 * WW;
    const int T4 = NB * NC * 36 * WW;
    int idx = blockIdx.x * blockDim.x + threadIdx.x;
    if (idx >= T2 + T4) return;
    int scale, H_out;
    float* dst;
    int li;
    if (idx < T2) { scale = 2; H_out = 72; dst = tmp2; li = idx; }
    else          { scale = 4; H_out = 36; dst = tmp4; li = idx - T2; }
    int w  = li % WW;
    int h  = (li / WW) % H_out;
    int bc = li / (WW * H_out);
    int t0 = scale * h + (scale >> 1) - 2;
    const float* s = gt + (size_t)bc * HH * WW + w;
    float acc = 0.0f;
    acc += -0.09375f * s[(size_t)iclamp(t0 + 0, 0, HH - 1) * WW];
    acc +=  0.59375f * s[(size_t)iclamp(t0 + 1, 0, HH - 1) * WW];
    acc +=  0.59375f * s[(size_t)iclamp(t0 + 2, 0, HH - 1) * WW];
    acc += -0.09375f * s[(size_t)iclamp(t0 + 3, 0, HH - 1) * WW];
    dst[li] = acc;
}

// ---- fused bicubic W-pass for both scales
__global__ void resize_w_all(const float* __restrict__ tmp2, const float* __restrict__ tmp4,
                             float* __restrict__ gt2, float* __restrict__ gt4) {
    const int T2 = NB * NC * 72 * 72;
    const int T4 = NB * NC * 36 * 36;
    int idx = blockIdx.x * blockDim.x + threadIdx.x;
    if (idx >= T2 + T4) return;
    int scale, H, W_out;
    const float* src;
    float* dst;
    int li;
    if (idx < T2) { scale = 2; H = 72; W_out = 72; src = tmp2; dst = gt2; li = idx; }
    else          { scale = 4; H = 36; W_out = 36; src = tmp4; dst = gt4; li = idx - T2; }
    int w  = li % W_out;
    int h  = (li / W_out) % H;
    int bc = li / (W_out * H);
    int t0 = scale * w + (scale >> 1) - 2;
    const float* s = src + ((size_t)bc * H + h) * WW;
    float acc = 0.0f;
    acc += -0.09375f * s[iclamp(t0 + 0, 0, WW - 1)];
    acc +=  0.59375f * s[iclamp(t0 + 1, 0, WW - 1)];
    acc +=  0.59375f * s[iclamp(t0 + 2, 0, WW - 1)];
    acc += -0.09375f * s[iclamp(t0 + 3, 0, WW - 1)];
    dst[li] = acc;
}

// ---- one patch-gram (helper)
__device__ __forceinline__ void do_patch(const float* __restrict__ src, int H, int W,
                                         int b, int n, float* __restrict__ d) {
    int PW = W / 3;
    int ph = n / PW, pw = n % PW;
    float p[3][9];
#pragma unroll
    for (int c = 0; c < 3; c++) {
        const float* s = src + ((size_t)b * NC + c) * H * W + (size_t)(ph * 3) * W + pw * 3;
#pragma unroll
        for (int i = 0; i < 3; i++)
#pragma unroll
            for (int j = 0; j < 3; j++)
                p[c][i * 3 + j] = s[i * W + j];
    }
#pragma unroll
    for (int c = 0; c < 3; c++)
#pragma unroll
        for (int e = 0; e < 3; e++) {
            float g = 0.0f;
#pragma unroll
            for (int q = 0; q < 9; q++) g += p[c][q] * p[e][q];
            d[c * 3 + e] = g / 27.0f;
        }
}

// ---- all 4 patch extractions in one launch (flat-range dispatch)
__global__ void patch_all(const float* __restrict__ x, const float* __restrict__ gt,
                          const float* __restrict__ gt2, const float* __restrict__ gt4,
                          float* __restrict__ p1, float* __restrict__ p2c) {
    const int R0 = NB * NPAT;   // x   -> p1
    const int R1 = NB * NPAT;   // gt  -> p2c @ 0
    const int R2 = NB * 576;    // gt2 -> p2c @ 2304
    const int R3 = NB * 144;    // gt4 -> p2c @ 2880
    int idx = blockIdx.x * blockDim.x + threadIdx.x;
    if (idx >= R0 + R1 + R2 + R3) return;
    if (idx < R0) {
        int b = idx / NPAT, n = idx % NPAT;
        do_patch(x, 144, 144, b, n, p1 + ((size_t)b * NPAT + n) * 9);
    } else if (idx < R0 + R1) {
        int li = idx - R0;
        int b = li / NPAT, n = li % NPAT;
        do_patch(gt, 144, 144, b, n, p2c + ((size_t)b * MCAT + n) * 9);
    } else if (idx < R0 + R1 + R2) {
        int li = idx - R0 - R1;
        int b = li / 576, n = li % 576;
        do_patch(gt2, 72, 72, b, n, p2c + ((size_t)b * MCAT + NPAT + n) * 9);
    } else {
        int li = idx - R0 - R1 - R2;
        int b = li / 144, n = li % 144;
        do_patch(gt4, 36, 36, b, n, p2c + ((size_t)b * MCAT + NPAT + 576 + n) * 9);
    }
}

// ---- score + argmin + |p1 - sel| partial sums.
// Block = 256 threads = 8 groups x 32 slices; each group owns 2 patches.
// Grid = 8 batches x 144 blocks = 1152.
__global__ __launch_bounds__(256) void score_kernel(const float* __restrict__ p1,
                                                    const float* __restrict__ p2cat,
                                                    float* __restrict__ partials) {
    __shared__ float cand[CHUNK * PAD];
    __shared__ float y2s[CHUNK];
    __shared__ float wsum[4];

    int t     = threadIdx.x;
    int slice = t & 31;
    int grp   = t >> 5;                   // 0..7
    int blk   = blockIdx.x;
    int b     = blk / BLOCKS_PER_B;
    int nbase = (blk % BLOCKS_PER_B) * PPB + grp * PPT;

    const float* CB = p2cat + (size_t)b * MCAT * 9;

    float a1[PPT][9], a2[PPT][9], x21[PPT], x22[PPT];
#pragma unroll
    for (int p = 0; p < PPT; p++) {
        const float* P1 = p1 + ((size_t)b * NPAT + nbase + p) * 9;
        const float* P2 = CB + (size_t)(nbase + p) * 9;   // rows [0,2304) of p2cat == p2
#pragma unroll
        for (int j = 0; j < 9; j++) { a1[p][j] = P1[j]; a2[p][j] = P2[j]; }
        float s1 = 0.0f, s2 = 0.0f;
#pragma unroll
        for (int j = 0; j < 9; j++) s1 += a1[p][j] * a1[p][j];
#pragma unroll
        for (int j = 0; j < 9; j++) s2 += a2[p][j] * a2[p][j];
        x21[p] = s1; x22[p] = s2;
    }

    float best[PPT]  = {INFINITY, INFINITY};
    int   besti[PPT] = {0x7fffffff, 0x7fffffff};

    for (int cb = 0; cb < MCAT; cb += CHUNK) {
        for (int i = t; i < CHUNK * 9; i += 256) {
            int c = i / 9, j = i % 9;
            cand[c * PAD + j] = CB[(size_t)cb * 9 + i];
        }
        for (int c = t; c < CHUNK; c += 256) {
            const float* cc = CB + (size_t)(cb + c) * 9;
            float s = 0.0f;
#pragma unroll
            for (int j = 0; j < 9; j++) s += cc[j] * cc[j];
            y2s[c] = s;
        }
        __syncthreads();

        for (int i = slice; i < CHUNK; i += 32) {
            const float* cv = cand + i * PAD;
            float v[9];
#pragma unroll
            for (int j = 0; j < 9; j++) v[j] = cv[j];
            float y2 = y2s[i];
            int   cg = cb + i;
#pragma unroll
            for (int p = 0; p < PPT; p++) {
                float d1 = 0.0f, d2 = 0.0f;
#pragma unroll
                for (int j = 0; j < 9; j++) { d1 += a1[p][j] * v[j]; d2 += a2[p][j] * v[j]; }
                float s1 = x21[p] + y2 - 2.0f * d1;
                float s2 = x22[p] + y2 - 2.0f * d2;
                float sc = 1.0f * s1 + 1.0f * s2;   // ALPHA = BETA = 1
                if (sc < best[p] || (sc == best[p] && cg < besti[p])) { best[p] = sc; besti[p] = cg; }
            }
        }
        __syncthreads();
    }

    // lexicographic (score, idx) min across the 32 slices (within each 32-lane half)
#pragma unroll
    for (int p = 0; p < PPT; p++) {
#pragma unroll
        for (int m = 1; m < 32; m <<= 1) {
            float ob = __shfl_xor(best[p], m);
            int   oi = __shfl_xor(besti[p], m);
            if (ob < best[p] || (ob == best[p] && oi < besti[p])) { best[p] = ob; besti[p] = oi; }
        }
    }

    float local = 0.0f;
    if (slice == 0) {
#pragma unroll
        for (int p = 0; p < PPT; p++) {
            const float* sel = CB + (size_t)besti[p] * 9;
#pragma unroll
            for (int j = 0; j < 9; j++) local += fabsf(a1[p][j] - sel[j]);
        }
    }
#pragma unroll
    for (int m = 1; m < 64; m <<= 1) local += __shfl_xor(local, m);
    if ((t & 63) == 0) wsum[t >> 6] = local;
    __syncthreads();
    if (t == 0) partials[blk] = (wsum[0] + wsum[1]) + (wsum[2] + wsum[3]);
}

__global__ void final_kernel(const float* __restrict__ partials, float* __restrict__ out) {
    int lane = threadIdx.x;
    float s = 0.0f;
    for (int i = lane; i < NBLK_SCORE; i += 64) s += partials[i];
#pragma unroll
    for (int m = 1; m < 64; m <<= 1) s += __shfl_xor(s, m);
    if (lane == 0) out[0] = s / 165888.0f;   // mean over 8*2304*9
}

extern "C" void kernel_launch(void* const* d_in, const int* in_sizes, int n_in,
                              void* d_out, int out_size, void* d_ws, size_t ws_size,
                              hipStream_t stream) {
    const float* x  = (const float*)d_in[0];
    const float* gt = (const float*)d_in[1];
    float* out = (float*)d_out;

    float* ws   = (float*)d_ws;
    float* tmp2 = ws;                         // [8,3,72,144]  = 248832
    float* tmp4 = tmp2 + NB * NC * 72 * 144;  // [8,3,36,144]  = 124416
    float* gt2  = tmp4 + NB * NC * 36 * 144;  // [8,3,72,72]   = 124416
    float* gt4  = gt2  + NB * NC * 72 * 72;   // [8,3,36,36]   =  31104
    float* p1   = gt4  + NB * NC * 36 * 36;   // [8,2304,9]    = 165888
    float* p2c  = p1   + (size_t)NB * NPAT * 9; // [8,3024,9]  = 217728
    float* parts= p2c  + (size_t)NB * MCAT * 9; // [1152]

    {
        int tot = NB * NC * 72 * WW + NB * NC * 36 * WW;
        resize_h_all<<<(tot + 255) / 256, 256, 0, stream>>>(gt, tmp2, tmp4);
    }
    {
        int tot = NB * NC * 72 * 72 + NB * NC * 36 * 36;
        resize_w_all<<<(tot + 255) / 256, 256, 0, stream>>>(tmp2, tmp4, gt2, gt4);
    }
    {
        int tot = NB * (NPAT + NPAT + 576 + 144);
        patch_all<<<(tot + 255) / 256, 256, 0, stream>>>(x, gt, gt2, gt4, p1, p2c);
    }
    score_kernel<<<NBLK_SCORE, 256, 0, stream>>>(p1, p2c, parts);
    final_kernel<<<1, 64, 0, stream>>>(parts, out);
}

// Round 3
// 76.659 us; speedup vs baseline: 2.1361x; 1.1160x over previous
//
#include <hip/hip_runtime.h>
#include <math.h>

#define NB 8
#define NC 3
#define HH 144
#define WW 144
#define NPAT 2304          // 48*48 patches of the 144x144 images
#define MCAT 3024          // 2304 + 576 + 144 real candidates
#define MCATP 3072         // padded to a multiple of 128 (guard rows)
#define CHUNK 384          // candidates staged per LDS round
#define PLANE4 96          // CHUNK/4 float4s per plane
#define STEPS 3            // CHUNK / (32 lanes * 4 cand)
#define NCHUNK 8           // MCATP / CHUNK
#define PPT 3              // patches per 32-lane group
#define GROUPS 4           // groups per 128-thread block
#define PPB (PPT * GROUPS) // 12 patches per block
#define BLOCKS_PER_B (NPAT / PPB)        // 192
#define NBLK_SCORE (NB * BLOCKS_PER_B)   // 1536

__device__ __forceinline__ int iclamp(int v, int lo, int hi) {
    return v < lo ? lo : (v > hi ? hi : v);
}

// ---- fused bicubic H-pass for both scales (frac always 0.5 -> constant taps)
__global__ void resize_h_all(const float* __restrict__ gt,
                             float* __restrict__ tmp2, float* __restrict__ tmp4) {
    const int T2 = NB * NC * 72 * WW;
    const int T4 = NB * NC * 36 * WW;
    int idx = blockIdx.x * blockDim.x + threadIdx.x;
    if (idx >= T2 + T4) return;
    int scale, H_out;
    float* dst;
    int li;
    if (idx < T2) { scale = 2; H_out = 72; dst = tmp2; li = idx; }
    else          { scale = 4; H_out = 36; dst = tmp4; li = idx - T2; }
    int w  = li % WW;
    int h  = (li / WW) % H_out;
    int bc = li / (WW * H_out);
    int t0 = scale * h + (scale >> 1) - 2;
    const float* s = gt + (size_t)bc * HH * WW + w;
    float acc = 0.0f;
    acc += -0.09375f * s[(size_t)iclamp(t0 + 0, 0, HH - 1) * WW];
    acc +=  0.59375f * s[(size_t)iclamp(t0 + 1, 0, HH - 1) * WW];
    acc +=  0.59375f * s[(size_t)iclamp(t0 + 2, 0, HH - 1) * WW];
    acc += -0.09375f * s[(size_t)iclamp(t0 + 3, 0, HH - 1) * WW];
    dst[li] = acc;
}

// ---- fused bicubic W-pass for both scales
__global__ void resize_w_all(const float* __restrict__ tmp2, const float* __restrict__ tmp4,
                             float* __restrict__ gt2, float* __restrict__ gt4) {
    const int T2 = NB * NC * 72 * 72;
    const int T4 = NB * NC * 36 * 36;
    int idx = blockIdx.x * blockDim.x + threadIdx.x;
    if (idx >= T2 + T4) return;
    int scale, H, W_out;
    const float* src;
    float* dst;
    int li;
    if (idx < T2) { scale = 2; H = 72; W_out = 72; src = tmp2; dst = gt2; li = idx; }
    else          { scale = 4; H = 36; W_out = 36; src = tmp4; dst = gt4; li = idx - T2; }
    int w  = li % W_out;
    int h  = (li / W_out) % H;
    int bc = li / (W_out * H);
    int t0 = scale * w + (scale >> 1) - 2;
    const float* s = src + ((size_t)bc * H + h) * WW;
    float acc = 0.0f;
    acc += -0.09375f * s[iclamp(t0 + 0, 0, WW - 1)];
    acc +=  0.59375f * s[iclamp(t0 + 1, 0, WW - 1)];
    acc +=  0.59375f * s[iclamp(t0 + 2, 0, WW - 1)];
    acc += -0.09375f * s[iclamp(t0 + 3, 0, WW - 1)];
    dst[li] = acc;
}

// ---- gram of one 3x3 patch into d[9]
__device__ __forceinline__ void patch_gram(const float* __restrict__ src, int H, int W,
                                           int b, int n, float* __restrict__ d) {
    int PW = W / 3;
    int ph = n / PW, pw = n % PW;
    float p[3][9];
#pragma unroll
    for (int c = 0; c < 3; c++) {
        const float* s = src + ((size_t)b * NC + c) * H * W + (size_t)(ph * 3) * W + pw * 3;
#pragma unroll
        for (int i = 0; i < 3; i++)
#pragma unroll
            for (int j = 0; j < 3; j++)
                p[c][i * 3 + j] = s[i * W + j];
    }
#pragma unroll
    for (int c = 0; c < 3; c++)
#pragma unroll
        for (int e = 0; e < 3; e++) {
            float g = 0.0f;
#pragma unroll
            for (int q = 0; q < 9; q++) g += p[c][q] * p[e][q];
            d[c * 3 + e] = g / 27.0f;
        }
}

// ---- all 4 patch extractions; p1 row-major, p2 transposed [b][9][MCATP] + y2 plane
__global__ void patch_all(const float* __restrict__ x, const float* __restrict__ gt,
                          const float* __restrict__ gt2, const float* __restrict__ gt4,
                          float* __restrict__ p1, float* __restrict__ p2cT,
                          float* __restrict__ y2c) {
    const int R0 = NB * NPAT;   // x   -> p1
    const int R1 = NB * NPAT;   // gt  -> p2cT m = n
    const int R2 = NB * 576;    // gt2 -> p2cT m = 2304 + n
    const int R3 = NB * 144;    // gt4 -> p2cT m = 2880 + n
    int idx = blockIdx.x * blockDim.x + threadIdx.x;
    if (idx >= R0 + R1 + R2 + R3) return;

    float d[9];
    if (idx < R0) {
        int b = idx / NPAT, n = idx % NPAT;
        patch_gram(x, 144, 144, b, n, d);
        float* dst = p1 + ((size_t)b * NPAT + n) * 9;
#pragma unroll
        for (int j = 0; j < 9; j++) dst[j] = d[j];
        return;
    }
    int b, m;
    if (idx < R0 + R1) {
        int li = idx - R0;
        b = li / NPAT; int n = li % NPAT;
        patch_gram(gt, 144, 144, b, n, d);
        m = n;
    } else if (idx < R0 + R1 + R2) {
        int li = idx - R0 - R1;
        b = li / 576; int n = li % 576;
        patch_gram(gt2, 72, 72, b, n, d);
        m = NPAT + n;
    } else {
        int li = idx - R0 - R1 - R2;
        b = li / 144; int n = li % 144;
        patch_gram(gt4, 36, 36, b, n, d);
        m = NPAT + 576 + n;
    }
    float y2 = 0.0f;
#pragma unroll
    for (int j = 0; j < 9; j++) {
        p2cT[((size_t)b * 9 + j) * MCATP + m] = d[j];
        y2 += d[j] * d[j];
    }
    y2c[(size_t)b * MCATP + m] = y2;
}

// ---- score + argmin + |p1 - sel| partial sums.
// Block = 128 threads = 4 groups x 32 lanes; each group owns 3 patches.
// Each lane processes 4 consecutive candidates per step via float4 LDS reads.
__global__ __launch_bounds__(128) void score_kernel(const float* __restrict__ p1,
                                                    const float* __restrict__ p2cT,
                                                    const float* __restrict__ y2c,
                                                    float* __restrict__ partials) {
    __shared__ float candT[9][CHUNK];
    __shared__ float y2s[CHUNK];
    __shared__ float wsum[2];

    int t     = threadIdx.x;
    int slice = t & 31;
    int grp   = t >> 5;
    int blk   = blockIdx.x;
    int b     = blk / BLOCKS_PER_B;
    int nbase = (blk % BLOCKS_PER_B) * PPB + grp * PPT;

    const float* PT = p2cT + (size_t)b * 9 * MCATP;
    const float* Y2 = y2c + (size_t)b * MCATP;

    float a1[PPT][9], a2[PPT][9], x21[PPT], x22[PPT];
#pragma unroll
    for (int p = 0; p < PPT; p++) {
        int n = nbase + p;
        const float* P1 = p1 + ((size_t)b * NPAT + n) * 9;
        float s1 = 0.0f;
#pragma unroll
        for (int j = 0; j < 9; j++) {
            a1[p][j] = P1[j];
            a2[p][j] = PT[(size_t)j * MCATP + n];   // rows [0,2304) of p2cat == p2
        }
#pragma unroll
        for (int j = 0; j < 9; j++) s1 += a1[p][j] * a1[p][j];
        x21[p] = s1;
        x22[p] = Y2[n];                              // same sequential sum, precomputed
    }

    float best[PPT];
    int   besti[PPT];
#pragma unroll
    for (int p = 0; p < PPT; p++) { best[p] = INFINITY; besti[p] = 0x7fffffff; }

    for (int cb = 0; cb < MCATP; cb += CHUNK) {
        // stage chunk: pure float4, conflict-free
        for (int i = t; i < 9 * PLANE4; i += 128) {
            int j = i / PLANE4, c4 = i - j * PLANE4;
            int g = cb + c4 * 4;
            float4 v;
            if (g < MCAT) v = *(const float4*)&PT[(size_t)j * MCATP + g];
            else          v = make_float4(0.f, 0.f, 0.f, 0.f);
            *(float4*)&candT[j][c4 * 4] = v;
        }
        for (int c4 = t; c4 < PLANE4; c4 += 128) {
            int g = cb + c4 * 4;
            float4 v;
            if (g < MCAT) v = *(const float4*)&Y2[g];
            else          v = make_float4(1e30f, 1e30f, 1e30f, 1e30f);  // guard: never wins
            *(float4*)&y2s[c4 * 4] = v;
        }
        __syncthreads();

#pragma unroll
        for (int s = 0; s < STEPS; s++) {
            int cl = s * 128 + slice * 4;
            float4 v[9];
#pragma unroll
            for (int j = 0; j < 9; j++) v[j] = *(const float4*)&candT[j][cl];
            float4 y4 = *(const float4*)&y2s[cl];
            int cg = cb + cl;
#pragma unroll
            for (int q = 0; q < 4; q++) {
                float y2 = (q == 0) ? y4.x : (q == 1) ? y4.y : (q == 2) ? y4.z : y4.w;
                int cgq = cg + q;
#pragma unroll
                for (int p = 0; p < PPT; p++) {
                    float d1 = 0.0f, d2 = 0.0f;
#pragma unroll
                    for (int j = 0; j < 9; j++) {
                        float vv = (q == 0) ? v[j].x : (q == 1) ? v[j].y : (q == 2) ? v[j].z : v[j].w;
                        d1 += a1[p][j] * vv;
                        d2 += a2[p][j] * vv;
                    }
                    float s1 = x21[p] + y2 - 2.0f * d1;
                    float s2 = x22[p] + y2 - 2.0f * d2;
                    float sc = 1.0f * s1 + 1.0f * s2;   // ALPHA = BETA = 1
                    if (sc < best[p] || (sc == best[p] && cgq < besti[p])) {
                        best[p] = sc; besti[p] = cgq;
                    }
                }
            }
        }
        __syncthreads();
    }

    // lexicographic (score, idx) min across the 32 lanes of the group
#pragma unroll
    for (int p = 0; p < PPT; p++) {
#pragma unroll
        for (int m = 1; m < 32; m <<= 1) {
            float ob = __shfl_xor(best[p], m);
            int   oi = __shfl_xor(besti[p], m);
            if (ob < best[p] || (ob == best[p] && oi < besti[p])) { best[p] = ob; besti[p] = oi; }
        }
    }

    float local = 0.0f;
    if (slice == 0) {
#pragma unroll
        for (int p = 0; p < PPT; p++) {
            int n = nbase + p;
            const float* P1 = p1 + ((size_t)b * NPAT + n) * 9;
            int bi = besti[p];
#pragma unroll
            for (int j = 0; j < 9; j++) local += fabsf(P1[j] - PT[(size_t)j * MCATP + bi]);
        }
    }
#pragma unroll
    for (int m = 1; m < 64; m <<= 1) local += __shfl_xor(local, m);
    if ((t & 63) == 0) wsum[t >> 6] = local;
    __syncthreads();
    if (t == 0) partials[blk] = wsum[0] + wsum[1];
}

__global__ void final_kernel(const float* __restrict__ partials, float* __restrict__ out) {
    int lane = threadIdx.x;
    float s = 0.0f;
    for (int i = lane; i < NBLK_SCORE; i += 64) s += partials[i];
#pragma unroll
    for (int m = 1; m < 64; m <<= 1) s += __shfl_xor(s, m);
    if (lane == 0) out[0] = s / 165888.0f;   // mean over 8*2304*9
}

extern "C" void kernel_launch(void* const* d_in, const int* in_sizes, int n_in,
                              void* d_out, int out_size, void* d_ws, size_t ws_size,
                              hipStream_t stream) {
    const float* x  = (const float*)d_in[0];
    const float* gt = (const float*)d_in[1];
    float* out = (float*)d_out;

    float* ws   = (float*)d_ws;
    float* tmp2 = ws;                           // [8,3,72,144]  = 248832
    float* tmp4 = tmp2 + NB * NC * 72 * 144;    // [8,3,36,144]  = 124416
    float* gt2  = tmp4 + NB * NC * 36 * 144;    // [8,3,72,72]   = 124416
    float* gt4  = gt2  + NB * NC * 72 * 72;     // [8,3,36,36]   =  31104
    float* p1   = gt4  + NB * NC * 36 * 36;     // [8,2304,9]    = 165888
    float* p2cT = p1   + (size_t)NB * NPAT * 9; // [8,9,3072]    = 221184
    float* y2c  = p2cT + (size_t)NB * 9 * MCATP;// [8,3072]      =  24576
    float* parts= y2c  + (size_t)NB * MCATP;    // [1536]

    {
        int tot = NB * NC * 72 * WW + NB * NC * 36 * WW;
        resize_h_all<<<(tot + 255) / 256, 256, 0, stream>>>(gt, tmp2, tmp4);
    }
    {
        int tot = NB * NC * 72 * 72 + NB * NC * 36 * 36;
        resize_w_all<<<(tot + 255) / 256, 256, 0, stream>>>(tmp2, tmp4, gt2, gt4);
    }
    {
        int tot = NB * (NPAT + NPAT + 576 + 144);
        patch_all<<<(tot + 255) / 256, 256, 0, stream>>>(x, gt, gt2, gt4, p1, p2cT, y2c);
    }
    score_kernel<<<NBLK_SCORE, 128, 0, stream>>>(p1, p2cT, y2c, parts);
    final_kernel<<<1, 64, 0, stream>>>(parts, out);
}